// Round 21
// baseline (433.461 us; speedup 1.0000x reference)
//
#include <hip/hip_runtime.h>

typedef _Float16 f16;
typedef f16 f16x8 __attribute__((ext_vector_type(8)));
typedef f16 f16x4 __attribute__((ext_vector_type(4)));
typedef float f32x4 __attribute__((ext_vector_type(4)));

#define QLEN 2048
#define BSZ 2
#define NH 16
#define DH 64
#define DM 1024
#define NBN (BSZ*NH)
#define SCALE 0.125f
#define QPRESCALE (0.125f * 1.44269504f)  // SCALE * log2(e), folded into Q

static __device__ __forceinline__ f32x4 mfma16(f16x8 a, f16x8 b, f32x4 c) {
  return __builtin_amdgcn_mfma_f32_16x16x32_f16(a, b, c, 0, 0, 0);
}

// async global->LDS, 16B per lane; lds dest = wave-uniform base + lane*16
static __device__ __forceinline__ void gload_lds16(const void* g, void* l) {
  __builtin_amdgcn_global_load_lds((const __attribute__((address_space(1))) unsigned int*)g,
                                   (__attribute__((address_space(3))) unsigned int*)l,
                                   16, 0, 0);
}

// LDS-only barrier (no memory clobber -> no vmcnt drain; rule #18 fencing)
static __device__ __forceinline__ void barrier_lds() {
  __builtin_amdgcn_sched_barrier(0);
  asm volatile("s_waitcnt lgkmcnt(0)");
  __builtin_amdgcn_s_barrier();
  __builtin_amdgcn_sched_barrier(0);
}

// ---------------- K0a: fp32 -> fp16 convert ----------------
__global__ __launch_bounds__(256) void cvt_f32_f16(const float* __restrict__ s,
                                                   f16* __restrict__ d, int n4) {
  int idx = blockIdx.x * 256 + threadIdx.x;
  if (idx >= n4) return;
  f32x4 v = ((const f32x4*)s)[idx];
  f16x4 o;
#pragma unroll
  for (int q = 0; q < 4; ++q) o[q] = (f16)v[q];
  ((f16x4*)d)[idx] = o;
}

// ---------------- K0b: QKV GEMM (R18: wave-contiguous epilogue) ------------
__global__ __launch_bounds__(256) void qkv_gemm(const f16* __restrict__ A, const f16* __restrict__ W,
                                                f16* __restrict__ Qs, f16* __restrict__ Ks,
                                                f16* __restrict__ Vt) {
  __shared__ f16 S[16384];
  f16* As = S;
  f16* Bs = S + 4096;
  const int bid = blockIdx.x;
  const int r0 = (bid & 31) << 7;
  const int c0 = (bid >> 5) << 7;
  const int t = threadIdx.x;
  const int lane = t & 63, w = t >> 6;
  const int wr = (w >> 1) << 6, wc = (w & 1) << 6;
  const int l15 = lane & 15, lhi = lane >> 4;

  f32x4 acc[4][4] = {};

  const f16* ga = A + (size_t)(r0 + (t >> 2)) * DM + ((t & 3) << 3);
  const f16* gb = W + (size_t)(c0 + (t >> 2)) * DM + ((t & 3) << 3);
  char* la = (char*)As + w * 1024;
  char* lb = (char*)Bs + w * 1024;

  for (int k0 = 0; k0 < DM; k0 += 32) {
    __syncthreads();
    gload_lds16(ga + k0, la);
    gload_lds16(ga + k0 + (size_t)64 * DM, la + 4096);
    gload_lds16(gb + k0, lb);
    gload_lds16(gb + k0 + (size_t)64 * DM, lb + 4096);
    __syncthreads();
    f16x8 af[4], bf[4];
#pragma unroll
    for (int m = 0; m < 4; ++m)
      af[m] = *(const f16x8*)&As[(wr + m * 16 + l15) * 32 + lhi * 8];
#pragma unroll
    for (int n = 0; n < 4; ++n)
      bf[n] = *(const f16x8*)&Bs[(wc + n * 16 + l15) * 32 + lhi * 8];
#pragma unroll
    for (int m = 0; m < 4; ++m)
#pragma unroll
      for (int n = 0; n < 4; ++n)
        acc[m][n] = mfma16(af[m], bf[n], acc[m][n]);
  }

  const int part = c0 >> 10;
  const int nh_base = (c0 >> 6) & 15;
  const int i0g = r0 >> 1;
  const float qs = (part == 0) ? QPRESCALE : 1.0f;

  __syncthreads();
#pragma unroll
  for (int m = 0; m < 4; ++m)
#pragma unroll
    for (int n = 0; n < 4; ++n)
#pragma unroll
      for (int q = 0; q < 4; ++q) {
        const int r_l = wr + m * 16 + lhi * 4 + q;
        const int c_l = wc + n * 16 + l15;
        const int i = r_l >> 1;
        const int d = c_l & 63;
        const int bn2 = ((r_l & 1) << 1) + (c_l >> 6);
        const f16 v = (f16)(acc[m][n][q] * qs);
        if (part < 2)
          S[(bn2 * 64 + i) * 64 + ((((d >> 3) ^ (i & 7)) << 3) | (d & 7))] = v;
        else
          S[(bn2 * 64 + d) * 64 + ((((i >> 3) ^ (d & 7)) << 3) | (i & 7))] = v;
      }
  __syncthreads();

  {
    const int bn2 = t >> 6;
    const int row7 = (t >> 3) & 7;
    const int o8 = t & 7;
    const int bn = ((bn2 >> 1) << 4) + nh_base + (bn2 & 1);
#pragma unroll
    for (int c = 0; c < 8; ++c) {
      const int row = row7 + c * 8;
      f16x8 v = *(const f16x8*)&S[(bn2 * 64 + row) * 64 + ((o8 ^ (row & 7)) << 3)];
      f16* dst;
      if (part == 0)      dst = Qs + ((size_t)bn * QLEN + i0g + row) * DH + o8 * 8;
      else if (part == 1) dst = Ks + ((size_t)bn * QLEN + i0g + row) * DH + o8 * 8;
      else                dst = Vt + ((size_t)bn * DH + row) * QLEN + i0g + o8 * 8;
      *(f16x8*)dst = v;
    }
  }
}

// ---------------- K1: flash attention v4 -- doubled occupancy --------------
// R21: grid NBN*32 (was NBN*16): each wave owns 16 i-rows (1 rowgroup),
// 4 blocks/CU -> 4 waves/SIMD (was 2) to hide L2 load latency under the
// short compute body. Swapped-operand QK^T + XCD-local bn (R17/R18) kept.
__global__ __launch_bounds__(256) void flash_attn(const f16* __restrict__ Qs, const f16* __restrict__ Ks,
                                                  const f16* __restrict__ Vt, float* __restrict__ av,
                                                  float* __restrict__ srl) {
  __shared__ f16 plds[4][16 * 40];
  const int bid = blockIdx.x;
  const int bn = bid & 31, ib = bid >> 5;  // ib 0..31
  const int t = threadIdx.x, lane = t & 63, w = t >> 6;
  const int l15 = lane & 15, lhi = lane >> 4;
  const int i0 = (ib << 6) + (w << 4);     // 16 rows per wave
  const f16* Qb = Qs + ((size_t)bn << 17);
  const f16* Kb = Ks + ((size_t)bn << 17);
  const f16* Vb = Vt + ((size_t)bn << 17);
  f16* pw = plds[w];

  f16x8 qf[2];
#pragma unroll
  for (int kc = 0; kc < 2; ++kc)
    qf[kc] = *(const f16x8*)&Qb[(size_t)(i0 + l15) * DH + kc * 32 + lhi * 8];

  f32x4 o[4] = {};
  float psum = 0.f;

  for (int j0 = 0; j0 < QLEN; j0 += 32) {
    f16x8 kf[2][2], vf[4];
#pragma unroll
    for (int jc = 0; jc < 2; ++jc)
#pragma unroll
      for (int kc = 0; kc < 2; ++kc)
        kf[jc][kc] = *(const f16x8*)&Kb[(size_t)(j0 + jc * 16 + l15) * DH + kc * 32 + lhi * 8];
#pragma unroll
    for (int dc = 0; dc < 4; ++dc)
      vf[dc] = *(const f16x8*)&Vb[(size_t)(dc * 16 + l15) * QLEN + j0 + lhi * 8];

    // S^T: zt[jc][q] = S[i=l15][j = jc*16 + lhi*4 + q]
    f32x4 zt[2];
#pragma unroll
    for (int jc = 0; jc < 2; ++jc) {
      f32x4 z = {0.f, 0.f, 0.f, 0.f};
      z = mfma16(kf[jc][0], qf[0], z);
      z = mfma16(kf[jc][1], qf[1], z);
      zt[jc] = z;
    }
    f16x4 pk[2];
    float ls = 0.f;
#pragma unroll
    for (int jc = 0; jc < 2; ++jc)
#pragma unroll
      for (int q = 0; q < 4; ++q) {
        float p = exp2f(zt[jc][q]);
        ls += p;
        pk[jc][q] = (f16)p;
      }
    psum += ls;
#pragma unroll
    for (int jc = 0; jc < 2; ++jc)
      *(f16x4*)&pw[l15 * 40 + jc * 16 + lhi * 4] = pk[jc];
    f16x8 pa = *(const f16x8*)&pw[l15 * 40 + lhi * 8];
#pragma unroll
    for (int dc = 0; dc < 4; ++dc)
      o[dc] = mfma16(pa, vf[dc], o[dc]);
  }

  // row-sum finalize: reduce over lhi groups, redistribute to C-layout rows
  float r = psum;
  r += __shfl_xor(r, 16);
  r += __shfl_xor(r, 32);
  const float lrun = r;  // row-sum for i = i0 + l15
  float rn[4];
#pragma unroll
  for (int q = 0; q < 4; ++q)
    rn[q] = __shfl(lrun, lhi * 4 + q);

  const int b = bn >> 4, nh = bn & 15;
#pragma unroll
  for (int dc = 0; dc < 4; ++dc)
#pragma unroll
    for (int q = 0; q < 4; ++q) {
      int i = i0 + lhi * 4 + q;
      av[((size_t)i * BSZ + b) * (NH * DH) + nh * DH + dc * 16 + l15] =
          o[dc][q] / rn[q];
    }
  if (lhi == 0)
    srl[bn * QLEN + i0 + l15] = 1.0f / lrun;
}

// ---------------- K2: materialize attn_prob (R18-exact) ------
#define LOADK(buf, chn)                                                        \
  do {                                                                         \
    _Pragma("unroll") for (int bl_ = 0; bl_ < 4; ++bl_) {                      \
      const f16* Kb_ = Ks + (((size_t)(w4 + bl_)) << 17) +                     \
                       (size_t)(j0 + (chn) * 16 + l15) * DH + lhi * 8;         \
      buf[bl_][0] = *(const f16x8*)(Kb_);                                      \
      buf[bl_][1] = *(const f16x8*)(Kb_ + 32);                                 \
    }                                                                          \
  } while (0)

#define SUBCHUNK(cur, nxt, ch, sub)                                            \
  do {                                                                         \
    f16 stv[4][4];                                                             \
    _Pragma("unroll") for (int bl_ = 0; bl_ < 4; ++bl_) {                      \
      f32x4 z = {0.f, 0.f, 0.f, 0.f};                                          \
      z = mfma16(qf[bl_][0], cur[bl_][0], z);                                  \
      z = mfma16(qf[bl_][1], cur[bl_][1], z);                                  \
      _Pragma("unroll") for (int q_ = 0; q_ < 4; ++q_)                         \
        stv[bl_][q_] = (f16)(exp2f(z[q_]) * rl[bl_][q_]);                      \
    }                                                                          \
    __builtin_amdgcn_sched_barrier(0);                                         \
    { const int nch_ = ((ch) + 1 < 16) ? (ch) + 1 : 15; LOADK(nxt, nch_); }    \
    __builtin_amdgcn_sched_barrier(0);                                         \
    _Pragma("unroll") for (int q_ = 0; q_ < 4; ++q_) {                         \
      const int i_l = lhi * 4 + q_;                                            \
      const int jl = (sub) * 16 + l15;                                         \
      f16x4 v = {stv[0][q_], stv[1][q_], stv[2][q_], stv[3][q_]};              \
      *(f16x4*)&tile[(i_l * 64 + jl) * 32 + ((w ^ (l15 & 7)) << 2)] = v;       \
    }                                                                          \
  } while (0)

__global__ __launch_bounds__(512, 1) void write_probs(const f16* __restrict__ Qs, const f16* __restrict__ Ks,
                                                      const float* __restrict__ srl,
                                                      float* __restrict__ pout) {
  __shared__ f16 tile[16 * 64 * 32];     // single 64 KiB tile
  const int bid = blockIdx.x;            // 1024 blocks
  const int it = bid >> 3, jt = bid & 7; // jt%8 -> XCD-local K panel
  const int i0 = it << 4, j0 = jt << 8;
  const int t = threadIdx.x, lane = t & 63, w = t >> 6;  // 8 waves, 4 bn each
  const int l15 = lane & 15, lhi = lane >> 4;
  const int w4 = w * 4;

  f16x8 qf[4][2];
  float rl[4][4];
#pragma unroll
  for (int bl = 0; bl < 4; ++bl) {
    const int bn = w4 + bl;
    const f16* Qb = Qs + ((size_t)bn << 17);
#pragma unroll
    for (int kc = 0; kc < 2; ++kc)
      qf[bl][kc] = *(const f16x8*)&Qb[(size_t)(i0 + l15) * DH + kc * 32 + lhi * 8];
#pragma unroll
    for (int q = 0; q < 4; ++q)
      rl[bl][q] = srl[bn * QLEN + i0 + lhi * 4 + q];
  }

  const int j_s = t >> 3;          // j within 64-span, 0..63
  const int o = t & 7;             // bn quad 0..7
  const int swz = o ^ (j_s & 7);

  f16x8 kfA[4][2], kfB[4][2];
  LOADK(kfA, 0);

  for (int ph = 0; ph < 4; ++ph) {
    const int c0 = ph * 4;
    SUBCHUNK(kfA, kfB, c0 + 0, 0);
    SUBCHUNK(kfB, kfA, c0 + 1, 1);
    SUBCHUNK(kfA, kfB, c0 + 2, 2);
    SUBCHUNK(kfB, kfA, c0 + 3, 3);
    barrier_lds();
#pragma unroll
    for (int r = 0; r < 16; ++r) {
      f16x4 v = *(const f16x4*)&tile[(r * 64 + j_s) * 32 + (swz << 2)];
      f32x4 ov = {(float)v[0], (float)v[1], (float)v[2], (float)v[3]};
      float* op = pout + ((size_t)(i0 + r) * QLEN + j0 + ph * 64 + j_s) * NBN + o * 4;
      __builtin_nontemporal_store(ov, (f32x4*)op);
    }
    barrier_lds();
  }
}

// ---------------- launcher ----------------
extern "C" void kernel_launch(void* const* d_in, const int* in_sizes, int n_in,
                              void* d_out, int out_size, void* d_ws, size_t ws_size,
                              hipStream_t stream) {
  const float* h  = (const float*)d_in[0];
  const float* wq = (const float*)d_in[1];
  float* av   = (float*)d_out;
  float* pout = av + (size_t)QLEN * BSZ * NH * DH;

  char* ws = (char*)d_ws;
  f16* hh  = (f16*)ws;                        // 8 MiB
  f16* wh  = (f16*)(ws + (8u << 20));         // 6 MiB
  f16* Qsc = (f16*)(ws + (16u << 20));        // 8 MiB
  f16* Ksc = (f16*)(ws + (24u << 20));        // 8 MiB
  f16* Vtc = (f16*)(ws + (32u << 20));        // 8 MiB
  float* srlv = (float*)(ws + (40u << 20));

  const int nh4 = QLEN * BSZ * DM / 4;
  const int nw4 = 3 * NH * DH * DM / 4;
  cvt_f32_f16<<<nh4 / 256, 256, 0, stream>>>(h, hh, nh4);
  cvt_f32_f16<<<nw4 / 256, 256, 0, stream>>>(wq, wh, nw4);
  qkv_gemm<<<32 * 24, 256, 0, stream>>>(hh, wh, Qsc, Ksc, Vtc);
  flash_attn<<<NBN * 32, 256, 0, stream>>>(Qsc, Ksc, Vtc, av, srlv);
  write_probs<<<128 * 8, 512, 0, stream>>>(Qsc, Ksc, srlv, pout);
}

// Round 22
// 320.146 us; speedup vs baseline: 1.3539x; 1.3539x over previous
//
#include <hip/hip_runtime.h>

typedef _Float16 f16;
typedef f16 f16x8 __attribute__((ext_vector_type(8)));
typedef f16 f16x4 __attribute__((ext_vector_type(4)));
typedef float f32x4 __attribute__((ext_vector_type(4)));

#define QLEN 2048
#define BSZ 2
#define NH 16
#define DH 64
#define DM 1024
#define NBN (BSZ*NH)
#define SCALE 0.125f
#define QPRESCALE (0.125f * 1.44269504f)  // SCALE * log2(e), folded into Q

static __device__ __forceinline__ f32x4 mfma16(f16x8 a, f16x8 b, f32x4 c) {
  return __builtin_amdgcn_mfma_f32_16x16x32_f16(a, b, c, 0, 0, 0);
}

// async global->LDS, 16B per lane; lds dest = wave-uniform base + lane*16
static __device__ __forceinline__ void gload_lds16(const void* g, void* l) {
  __builtin_amdgcn_global_load_lds((const __attribute__((address_space(1))) unsigned int*)g,
                                   (__attribute__((address_space(3))) unsigned int*)l,
                                   16, 0, 0);
}

// LDS-only barrier (no memory clobber -> no vmcnt drain; rule #18 fencing)
static __device__ __forceinline__ void barrier_lds() {
  __builtin_amdgcn_sched_barrier(0);
  asm volatile("s_waitcnt lgkmcnt(0)");
  __builtin_amdgcn_s_barrier();
  __builtin_amdgcn_sched_barrier(0);
}

// ---------------- K0a: fp32 -> fp16 convert ----------------
__global__ __launch_bounds__(256) void cvt_f32_f16(const float* __restrict__ s,
                                                   f16* __restrict__ d, int n4) {
  int idx = blockIdx.x * 256 + threadIdx.x;
  if (idx >= n4) return;
  f32x4 v = ((const f32x4*)s)[idx];
  f16x4 o;
#pragma unroll
  for (int q = 0; q < 4; ++q) o[q] = (f16)v[q];
  ((f16x4*)d)[idx] = o;
}

// ---------------- K0b: QKV GEMM (R18: wave-contiguous epilogue) ------------
__global__ __launch_bounds__(256) void qkv_gemm(const f16* __restrict__ A, const f16* __restrict__ W,
                                                f16* __restrict__ Qs, f16* __restrict__ Ks,
                                                f16* __restrict__ Vt) {
  __shared__ f16 S[16384];
  f16* As = S;
  f16* Bs = S + 4096;
  const int bid = blockIdx.x;
  const int r0 = (bid & 31) << 7;
  const int c0 = (bid >> 5) << 7;
  const int t = threadIdx.x;
  const int lane = t & 63, w = t >> 6;
  const int wr = (w >> 1) << 6, wc = (w & 1) << 6;
  const int l15 = lane & 15, lhi = lane >> 4;

  f32x4 acc[4][4] = {};

  const f16* ga = A + (size_t)(r0 + (t >> 2)) * DM + ((t & 3) << 3);
  const f16* gb = W + (size_t)(c0 + (t >> 2)) * DM + ((t & 3) << 3);
  char* la = (char*)As + w * 1024;
  char* lb = (char*)Bs + w * 1024;

  for (int k0 = 0; k0 < DM; k0 += 32) {
    __syncthreads();
    gload_lds16(ga + k0, la);
    gload_lds16(ga + k0 + (size_t)64 * DM, la + 4096);
    gload_lds16(gb + k0, lb);
    gload_lds16(gb + k0 + (size_t)64 * DM, lb + 4096);
    __syncthreads();
    f16x8 af[4], bf[4];
#pragma unroll
    for (int m = 0; m < 4; ++m)
      af[m] = *(const f16x8*)&As[(wr + m * 16 + l15) * 32 + lhi * 8];
#pragma unroll
    for (int n = 0; n < 4; ++n)
      bf[n] = *(const f16x8*)&Bs[(wc + n * 16 + l15) * 32 + lhi * 8];
#pragma unroll
    for (int m = 0; m < 4; ++m)
#pragma unroll
      for (int n = 0; n < 4; ++n)
        acc[m][n] = mfma16(af[m], bf[n], acc[m][n]);
  }

  const int part = c0 >> 10;
  const int nh_base = (c0 >> 6) & 15;
  const int i0g = r0 >> 1;
  const float qs = (part == 0) ? QPRESCALE : 1.0f;

  __syncthreads();
#pragma unroll
  for (int m = 0; m < 4; ++m)
#pragma unroll
    for (int n = 0; n < 4; ++n)
#pragma unroll
      for (int q = 0; q < 4; ++q) {
        const int r_l = wr + m * 16 + lhi * 4 + q;
        const int c_l = wc + n * 16 + l15;
        const int i = r_l >> 1;
        const int d = c_l & 63;
        const int bn2 = ((r_l & 1) << 1) + (c_l >> 6);
        const f16 v = (f16)(acc[m][n][q] * qs);
        if (part < 2)
          S[(bn2 * 64 + i) * 64 + ((((d >> 3) ^ (i & 7)) << 3) | (d & 7))] = v;
        else
          S[(bn2 * 64 + d) * 64 + ((((i >> 3) ^ (d & 7)) << 3) | (i & 7))] = v;
      }
  __syncthreads();

  {
    const int bn2 = t >> 6;
    const int row7 = (t >> 3) & 7;
    const int o8 = t & 7;
    const int bn = ((bn2 >> 1) << 4) + nh_base + (bn2 & 1);
#pragma unroll
    for (int c = 0; c < 8; ++c) {
      const int row = row7 + c * 8;
      f16x8 v = *(const f16x8*)&S[(bn2 * 64 + row) * 64 + ((o8 ^ (row & 7)) << 3)];
      f16* dst;
      if (part == 0)      dst = Qs + ((size_t)bn * QLEN + i0g + row) * DH + o8 * 8;
      else if (part == 1) dst = Ks + ((size_t)bn * QLEN + i0g + row) * DH + o8 * 8;
      else                dst = Vt + ((size_t)bn * DH + row) * QLEN + i0g + o8 * 8;
      *(f16x8*)dst = v;
    }
  }
}

// ---------------- K1: flash attention v3 + XCD-local grid (R18-exact) ------
__global__ __launch_bounds__(256) void flash_attn(const f16* __restrict__ Qs, const f16* __restrict__ Ks,
                                                  const f16* __restrict__ Vt, float* __restrict__ av,
                                                  float* __restrict__ srl) {
  __shared__ f16 plds[4][16 * 40];
  const int bid = blockIdx.x;
  const int bn = bid & 31, ib = bid >> 5;
  const int t = threadIdx.x, lane = t & 63, w = t >> 6;
  const int l15 = lane & 15, lhi = lane >> 4;
  const int i0 = (ib << 7) + (w << 5);
  const f16* Qb = Qs + ((size_t)bn << 17);
  const f16* Kb = Ks + ((size_t)bn << 17);
  const f16* Vb = Vt + ((size_t)bn << 17);
  f16* pw = plds[w];

  f16x8 qf[2][2];
#pragma unroll
  for (int rg = 0; rg < 2; ++rg)
#pragma unroll
    for (int kc = 0; kc < 2; ++kc)
      qf[rg][kc] = *(const f16x8*)&Qb[(size_t)(i0 + rg * 16 + l15) * DH + kc * 32 + lhi * 8];

  f32x4 o[2][4] = {};
  float psum[2] = {};

  for (int j0 = 0; j0 < QLEN; j0 += 32) {
    f16x8 kf[2][2], vf[4];
#pragma unroll
    for (int jc = 0; jc < 2; ++jc)
#pragma unroll
      for (int kc = 0; kc < 2; ++kc)
        kf[jc][kc] = *(const f16x8*)&Kb[(size_t)(j0 + jc * 16 + l15) * DH + kc * 32 + lhi * 8];
#pragma unroll
    for (int dc = 0; dc < 4; ++dc)
      vf[dc] = *(const f16x8*)&Vb[(size_t)(dc * 16 + l15) * QLEN + j0 + lhi * 8];

#pragma unroll
    for (int rg = 0; rg < 2; ++rg) {
      f32x4 zt[2];
#pragma unroll
      for (int jc = 0; jc < 2; ++jc) {
        f32x4 z = {0.f, 0.f, 0.f, 0.f};
        z = mfma16(kf[jc][0], qf[rg][0], z);
        z = mfma16(kf[jc][1], qf[rg][1], z);
        zt[jc] = z;
      }
      f16x4 pk[2];
      float ls = 0.f;
#pragma unroll
      for (int jc = 0; jc < 2; ++jc)
#pragma unroll
        for (int q = 0; q < 4; ++q) {
          float p = exp2f(zt[jc][q]);
          ls += p;
          pk[jc][q] = (f16)p;
        }
      psum[rg] += ls;
#pragma unroll
      for (int jc = 0; jc < 2; ++jc)
        *(f16x4*)&pw[l15 * 40 + jc * 16 + lhi * 4] = pk[jc];
      f16x8 pa = *(const f16x8*)&pw[l15 * 40 + lhi * 8];
#pragma unroll
      for (int dc = 0; dc < 4; ++dc)
        o[rg][dc] = mfma16(pa, vf[dc], o[rg][dc]);
    }
  }

  float lrun[2], rn[2][4];
#pragma unroll
  for (int rg = 0; rg < 2; ++rg) {
    float r = psum[rg];
    r += __shfl_xor(r, 16);
    r += __shfl_xor(r, 32);
    lrun[rg] = r;
#pragma unroll
    for (int q = 0; q < 4; ++q)
      rn[rg][q] = __shfl(lrun[rg], lhi * 4 + q);
  }

  const int b = bn >> 4, nh = bn & 15;
#pragma unroll
  for (int rg = 0; rg < 2; ++rg)
#pragma unroll
    for (int dc = 0; dc < 4; ++dc)
#pragma unroll
      for (int q = 0; q < 4; ++q) {
        int i = i0 + rg * 16 + lhi * 4 + q;
        av[((size_t)i * BSZ + b) * (NH * DH) + nh * DH + dc * 16 + l15] =
            o[rg][dc][q] / rn[rg][q];
      }
  if (lhi == 0) {
#pragma unroll
    for (int rg = 0; rg < 2; ++rg)
      srl[bn * QLEN + i0 + rg * 16 + l15] = 1.0f / lrun[rg];
  }
}

// ---------------- K2: materialize attn_prob -- f32 tile (cvt-free store) ---
// R22 A/B: convert to f32 at DEPOSIT; tile = f32 [16i][32j][32bn] = 64KB,
// 8 phases of 32 j. Store phase is pure ds_read_b128 + store_dwordx4 (no
// cvt) but rows shrink 8KB -> 4KB. Decides issue-density vs burst-size.
#define LOADK(buf, chn)                                                        \
  do {                                                                         \
    _Pragma("unroll") for (int bl_ = 0; bl_ < 4; ++bl_) {                      \
      const f16* Kb_ = Ks + (((size_t)(w4 + bl_)) << 17) +                     \
                       (size_t)(j0 + (chn) * 16 + l15) * DH + lhi * 8;         \
      buf[bl_][0] = *(const f16x8*)(Kb_);                                      \
      buf[bl_][1] = *(const f16x8*)(Kb_ + 32);                                 \
    }                                                                          \
  } while (0)

// compute subchunk ch, prefetch ch+1, deposit f32x4 into tile
#define SUBCHUNK(cur, nxt, ch, sub)                                            \
  do {                                                                         \
    float stv[4][4];                                                           \
    _Pragma("unroll") for (int bl_ = 0; bl_ < 4; ++bl_) {                      \
      f32x4 z = {0.f, 0.f, 0.f, 0.f};                                          \
      z = mfma16(qf[bl_][0], cur[bl_][0], z);                                  \
      z = mfma16(qf[bl_][1], cur[bl_][1], z);                                  \
      _Pragma("unroll") for (int q_ = 0; q_ < 4; ++q_)                         \
        stv[bl_][q_] = exp2f(z[q_]) * rl[bl_][q_];                             \
    }                                                                          \
    __builtin_amdgcn_sched_barrier(0);                                         \
    { const int nch_ = ((ch) + 1 < 16) ? (ch) + 1 : 15; LOADK(nxt, nch_); }    \
    __builtin_amdgcn_sched_barrier(0);                                         \
    _Pragma("unroll") for (int q_ = 0; q_ < 4; ++q_) {                         \
      const int i_l = lhi * 4 + q_;                                            \
      const int jl = (sub) * 16 + l15;                                         \
      f32x4 v = {stv[0][q_], stv[1][q_], stv[2][q_], stv[3][q_]};              \
      *(f32x4*)&tile[(i_l * 32 + jl) * 32 + ((w ^ (jl & 7)) << 2)] = v;        \
    }                                                                          \
  } while (0)

__global__ __launch_bounds__(512, 1) void write_probs(const f16* __restrict__ Qs, const f16* __restrict__ Ks,
                                                      const float* __restrict__ srl,
                                                      float* __restrict__ pout) {
  __shared__ float tile[16 * 32 * 32];   // 64 KiB f32
  const int bid = blockIdx.x;            // 1024 blocks
  const int it = bid >> 3, jt = bid & 7; // jt%8 -> XCD-local K panel
  const int i0 = it << 4, j0 = jt << 8;
  const int t = threadIdx.x, lane = t & 63, w = t >> 6;  // 8 waves, 4 bn each
  const int l15 = lane & 15, lhi = lane >> 4;
  const int w4 = w * 4;

  // hoisted per-block state: Q frags + row 1/l for this wave's 4 bn
  f16x8 qf[4][2];
  float rl[4][4];
#pragma unroll
  for (int bl = 0; bl < 4; ++bl) {
    const int bn = w4 + bl;
    const f16* Qb = Qs + ((size_t)bn << 17);
#pragma unroll
    for (int kc = 0; kc < 2; ++kc)
      qf[bl][kc] = *(const f16x8*)&Qb[(size_t)(i0 + l15) * DH + kc * 32 + lhi * 8];
#pragma unroll
    for (int q = 0; q < 4; ++q)
      rl[bl][q] = srl[bn * QLEN + i0 + lhi * 4 + q];
  }

  // store-phase lane mapping: each pass covers 2 i-rows (512 thr x 16B = 8KB)
  const int rpar = t >> 8;         // row parity 0/1
  const int j_s = (t >> 3) & 31;   // j within 32-span
  const int o = t & 7;             // bn quad 0..7
  const int swz = o ^ (j_s & 7);

  f16x8 kfA[4][2], kfB[4][2];
  LOADK(kfA, 0);

  for (int ph = 0; ph < 8; ++ph) {
    const int c0 = ph * 2;
    const int jbase = j0 + ph * 32;
    SUBCHUNK(kfA, kfB, c0 + 0, 0);
    SUBCHUNK(kfB, kfA, c0 + 1, 1);
    barrier_lds();  // deposits visible; stores may begin (no vmem drain)
#pragma unroll
    for (int r = 0; r < 8; ++r) {
      const int row = r * 2 + rpar;
      f32x4 v = *(const f32x4*)&tile[(row * 32 + j_s) * 32 + (swz << 2)];
      float* op = pout + ((size_t)(i0 + row) * QLEN + jbase + j_s) * NBN + o * 4;
      __builtin_nontemporal_store(v, (f32x4*)op);
    }
    barrier_lds();  // ds_reads done -> tile reusable; stores keep flying
  }
}

// ---------------- launcher ----------------
extern "C" void kernel_launch(void* const* d_in, const int* in_sizes, int n_in,
                              void* d_out, int out_size, void* d_ws, size_t ws_size,
                              hipStream_t stream) {
  const float* h  = (const float*)d_in[0];
  const float* wq = (const float*)d_in[1];
  float* av   = (float*)d_out;
  float* pout = av + (size_t)QLEN * BSZ * NH * DH;

  char* ws = (char*)d_ws;
  f16* hh  = (f16*)ws;                        // 8 MiB
  f16* wh  = (f16*)(ws + (8u << 20));         // 6 MiB
  f16* Qsc = (f16*)(ws + (16u << 20));        // 8 MiB
  f16* Ksc = (f16*)(ws + (24u << 20));        // 8 MiB
  f16* Vtc = (f16*)(ws + (32u << 20));        // 8 MiB
  float* srlv = (float*)(ws + (40u << 20));

  const int nh4 = QLEN * BSZ * DM / 4;
  const int nw4 = 3 * NH * DH * DM / 4;
  cvt_f32_f16<<<nh4 / 256, 256, 0, stream>>>(h, hh, nh4);
  cvt_f32_f16<<<nw4 / 256, 256, 0, stream>>>(wq, wh, nw4);
  qkv_gemm<<<32 * 24, 256, 0, stream>>>(hh, wh, Qsc, Ksc, Vtc);
  flash_attn<<<NBN * 16, 256, 0, stream>>>(Qsc, Ksc, Vtc, av, srlv);
  write_probs<<<128 * 8, 512, 0, stream>>>(Qsc, Ksc, srlv, pout);
}